// Round 8
// baseline (406.519 us; speedup 1.0000x reference)
//
#include <hip/hip_runtime.h>
#include <math.h>

#define HH 128
#define WW 128
#define HWSZ (128*128)

typedef __attribute__((ext_vector_type(8))) short short8;
typedef __attribute__((ext_vector_type(4))) float float4v;
typedef __attribute__((ext_vector_type(2))) unsigned uint2v;

__device__ inline short f2bf(float f) {
  unsigned x = __float_as_uint(f);
  unsigned r = (x + 0x7fffu + ((x >> 16) & 1u)) >> 16;
  return (short)r;
}
__device__ inline float bf2f(unsigned short u) {
  return __uint_as_float(((unsigned)u) << 16);
}
// XOR-swizzled short-index of 8-short granule g in LDS row `row` (row stride 32 shorts).
__device__ inline int swz(int row, int g) {
  return row * 32 + ((g ^ ((row >> 1) & 3)) << 3);
}

// ---------------- prep1: xcvt (blocks 0..511) + wcvt3 p1/p2 (blocks 512..2815) ----
__global__ __launch_bounds__(256) void prep1_kernel(
    const float* __restrict__ x, short* __restrict__ xbf,
    const float* __restrict__ w_p1, const float* __restrict__ g_p1, const float* __restrict__ v_p1,
    const float* __restrict__ w_p2, const float* __restrict__ g_p2, const float* __restrict__ v_p2,
    short* __restrict__ wb12) {
  __shared__ short tile[32 * 264];
  const int bid = blockIdx.x;
  const int t = threadIdx.x;
  if (bid < 512) {
    // ---- x: NCHW fp32 -> NHWC bf16 (round-0 xcvt body) ----
    const int h = bid & 127, b = bid >> 7;
    for (int wc = 0; wc < 4; wc++) {
      const int w0 = wc * 32;
      __syncthreads();
      #pragma unroll
      for (int coi = 0; coi < 8; coi++) {
        int ci = coi * 32 + (t >> 3);
        int wq = t & 7;
        float4v f = *(const float4v*)&x[((size_t)b * 256 + ci) * HWSZ + h * WW + w0 + wq * 4];
        tile[(wq * 4 + 0) * 264 + ci] = f2bf(f.x);
        tile[(wq * 4 + 1) * 264 + ci] = f2bf(f.y);
        tile[(wq * 4 + 2) * 264 + ci] = f2bf(f.z);
        tile[(wq * 4 + 3) * 264 + ci] = f2bf(f.w);
      }
      __syncthreads();
      #pragma unroll
      for (int pass = 0; pass < 4; pass++) {
        int wl = pass * 8 + (t >> 5);
        int ci8 = (t & 31) * 8;
        short8 v = *(const short8*)&tile[wl * 264 + ci8];
        *(short8*)&xbf[(((size_t)b * HH + h) * WW + w0 + wl) * 256 + ci8] = v;
      }
    }
  } else {
    // ---- weights p1|p2 (BN scale folded), 589824 elems ----
    int e = (bid - 512) * 256 + t;
    if (e >= 589824) return;
    const float* w; const float* g; const float* v; int co_off;
    if (e < 294912) { w = w_p1; g = g_p1; v = v_p1; co_off = 0; }
    else { e -= 294912; w = w_p2; g = g_p2; v = v_p2; co_off = 128; }
    int t9 = e % 9;
    int ci = (e / 9) & 255;
    int co = e / (9 * 256);
    float s = g[co] * rsqrtf(v[co] + 1e-5f);
    wb12[((size_t)t9 * 256 + co_off + co) * 256 + ci] = f2bf(w[e] * s);
  }
}

// ---------------- prep2: wcvt3 c1 + wcvt1 c2 + wcvt3 p3 ----
__global__ __launch_bounds__(256) void prep2_kernel(
    const float* __restrict__ w_c1, const float* __restrict__ g_c1, const float* __restrict__ v_c1,
    const float* __restrict__ w_c2, const float* __restrict__ g_c2, const float* __restrict__ v_c2,
    const float* __restrict__ w_p3, const float* __restrict__ g_p3, const float* __restrict__ v_p3,
    short* __restrict__ wbc1, short* __restrict__ wbc2, short* __restrict__ wbp3) {
  int e = blockIdx.x * 256 + threadIdx.x;
  if (e < 294912) {
    int t9 = e % 9;
    int ci = (e / 9) & 127;
    int co = e / (9 * 128);
    float s = g_c1[co] * rsqrtf(v_c1[co] + 1e-5f);
    wbc1[((size_t)t9 * 256 + co) * 128 + ci] = f2bf(w_c1[e] * s);
  } else if (e < 360448) {
    int e2 = e - 294912;
    int co = e2 >> 8;
    float s = g_c2[co] * rsqrtf(v_c2[co] + 1e-5f);
    wbc2[e2] = f2bf(w_c2[e2] * s);
  } else if (e < 950272) {
    int e3 = e - 360448;                      // 589824 elems, [256co][256ci][3][3]
    int t9 = e3 % 9;
    int ci = (e3 / 9) & 255;
    int co = e3 / (9 * 256);
    float s = g_p3[co] * rsqrtf(v_p3[co] + 1e-5f);
    wbp3[((size_t)t9 * 256 + co) * 256 + ci] = f2bf(w_p3[e3] * s);
  }
}

// ---------------- MFMA implicit-GEMM conv3x3 (+optional fused 1x1), SW-pipelined ----------------
// Block: 256 thr = 4 waves. Tile: M=128 px (one image row) x N=256 co (ALL couts).
// Wave tile: 64 px x 128 co (acc[4][8]). LDS 56.5 KB single-buffer -> 2 blocks/CU;
// the two resident blocks run antiphase so one block's store/barrier phase is covered
// by the other's MFMA phase (the proven round-0 structure; all restructures regressed:
// r1-r3 spilled at 8-wave geometry, r4 lost antiphase at 1 block/CU).
// Register-file arithmetic: acc=128/wave caps occupancy at 2 waves/SIMD; 2 blocks x
// 4 waves is the only filling that keeps antiphase. Conv is structurally ceilinged
// at ~34% MfmaUtil in this framework.
template<int CIN_A, bool PHASE_B, int SHIFT_MODE, bool SPLIT_OUT, bool OUT_F32>
__global__ __launch_bounds__(256, 2) void conv_mfma(
    const short* __restrict__ srcA, const short* __restrict__ xB,
    const short* __restrict__ wbA, const short* __restrict__ wbB,
    const float* __restrict__ g0, const float* __restrict__ b0,
    const float* __restrict__ m0, const float* __restrict__ v0,
    const float* __restrict__ g1, const float* __restrict__ b1,
    const float* __restrict__ m1, const float* __restrict__ v1,
    void* __restrict__ out0, void* __restrict__ out1)
{
  __shared__ short A_s[130 * 32];
  __shared__ short B_s[3 * 256 * 32];

  const int tid  = threadIdx.x;
  const int wave = tid >> 6;
  const int lane = tid & 63;
  const int wm = wave & 1;          // px half (64)
  const int wn = wave >> 1;         // co half (128)
  const int lr = lane & 15;
  const int lk = lane >> 4;

  const int h  = blockIdx.x & 127;
  const int b  = blockIdx.x >> 7;

  constexpr int ncA = CIN_A / 32;
  const int dystart = (h == 0) ? 1 : 0;
  const int dyend   = (h == HH - 1) ? 2 : 3;
  const int chunksA = (dyend - dystart) * ncA;
  const int total   = chunksA + (PHASE_B ? 8 : 0);

  float4v acc[4][8];
  #pragma unroll
  for (int i = 0; i < 4; i++)
    #pragma unroll
    for (int j = 0; j < 8; j++) acc[i][j] = (float4v)(0.0f);

  // pipeline registers
  short8 rA[3], rB[12];
  const short* aRow = nullptr;
  const short* bBase = nullptr;
  bool curIsA = true;

  auto decode = [&](int t, const short*& ar, const short*& bb, bool& isA) {
    isA = (t < chunksA);
    if (isA) {
      int dy  = dystart + t / ncA;
      int ci0 = (t % ncA) * 32;
      ar = srcA + (((size_t)b * HH + (h + dy - 1)) * WW) * CIN_A + ci0;
      bb = wbA + ((size_t)(dy * 3) * 256) * CIN_A + ci0;
    } else {
      int ci0 = (t - chunksA) * 32;
      ar = xB + (((size_t)b * HH + h) * WW) * 256 + ci0;
      bb = wbB + ci0;
    }
  };

  auto loadRegs = [&](const short* ar, const short* bb, bool isA) {
    if (isA) {
      #pragma unroll
      for (int i = 0; i < 2; i++) {
        int idx = tid + i * 256;
        int w = (idx >> 2) - 1, q = idx & 3;
        rA[i] = ((unsigned)w < (unsigned)WW)
                  ? *(const short8*)(ar + (size_t)w * CIN_A + q * 8) : (short8)(0);
      }
      if (tid < 8) {
        int idx = tid + 512;
        int w = (idx >> 2) - 1, q = idx & 3;
        rA[2] = ((unsigned)w < (unsigned)WW)
                  ? *(const short8*)(ar + (size_t)w * CIN_A + q * 8) : (short8)(0);
      }
      // B: 3 dx x 256 co x 4 q = 3072 granules -> 12/thread
      #pragma unroll
      for (int i = 0; i < 12; i++) {
        int idx = tid + i * 256;
        int dx = idx >> 10, rem = idx & 1023;
        int co = rem >> 2, q = rem & 3;
        rB[i] = *(const short8*)(bb + (size_t)(dx * 256 + co) * CIN_A + q * 8);
      }
    } else {
      #pragma unroll
      for (int i = 0; i < 2; i++) {
        int idx = tid + i * 256;
        int wp = idx >> 2, q = idx & 3;
        rA[i] = *(const short8*)(ar + (size_t)wp * 256 + q * 8);
      }
      // B: 256 co x 4 q = 1024 granules -> 4/thread
      #pragma unroll
      for (int i = 0; i < 4; i++) {
        int idx = tid + i * 256;
        int co = idx >> 2, q = idx & 3;
        rB[i] = *(const short8*)(bb + (size_t)co * 256 + q * 8);
      }
    }
  };

  auto storeLDS = [&](bool isA) {
    if (isA) {
      #pragma unroll
      for (int i = 0; i < 2; i++) {
        int idx = tid + i * 256;
        *(short8*)&A_s[swz(idx >> 2, idx & 3)] = rA[i];
      }
      if (tid < 8) {
        int idx = tid + 512;
        *(short8*)&A_s[swz(idx >> 2, idx & 3)] = rA[2];
      }
      #pragma unroll
      for (int i = 0; i < 12; i++) {
        int idx = tid + i * 256;
        int dx = idx >> 10, rem = idx & 1023;
        *(short8*)&B_s[swz(dx * 256 + (rem >> 2), rem & 3)] = rB[i];
      }
    } else {
      #pragma unroll
      for (int i = 0; i < 2; i++) {
        int idx = tid + i * 256;
        *(short8*)&A_s[swz(idx >> 2, idx & 3)] = rA[i];
      }
      #pragma unroll
      for (int i = 0; i < 4; i++) {
        int idx = tid + i * 256;
        *(short8*)&B_s[swz(idx >> 2, idx & 3)] = rB[i];
      }
    }
  };

  // prologue
  decode(0, aRow, bBase, curIsA);
  loadRegs(aRow, bBase, curIsA);

  for (int t = 0; t < total; t++) {
    bool isA = curIsA;
    __syncthreads();            // previous MFMA done reading LDS
    storeLDS(isA);              // waits on this chunk's global loads
    __syncthreads();
    if (t + 1 < total) {        // issue next chunk's loads; overlap with MFMA below
      decode(t + 1, aRow, bBase, curIsA);
      loadRegs(aRow, bBase, curIsA);
    }
    const int ndx = isA ? 3 : 1;
    for (int dx = 0; dx < ndx; dx++) {
      short8 af[4];
      #pragma unroll
      for (int mi = 0; mi < 4; mi++)
        af[mi] = *(const short8*)&A_s[swz(wm * 64 + mi * 16 + lr + dx, lk)];
      #pragma unroll
      for (int ni = 0; ni < 8; ni++) {
        short8 bfr = *(const short8*)&B_s[swz(dx * 256 + wn * 128 + ni * 16 + lr, lk)];
        #pragma unroll
        for (int mi = 0; mi < 4; mi++)
          acc[mi][ni] = __builtin_amdgcn_mfma_f32_16x16x32_bf16(af[mi], bfr, acc[mi][ni], 0, 0, 0);
      }
    }
  }

  // ---------- epilogue: +shift (from raw BN params), relu, store ----------
  #pragma unroll
  for (int ni = 0; ni < 8; ni++) {
    int c = wn * 128 + ni * 16 + lr;          // co 0..255
    float sh;
    if (SHIFT_MODE == 0) {
      float s = g0[c] * rsqrtf(v0[c] + 1e-5f);
      sh = b0[c] - m0[c] * s;
    } else if (SHIFT_MODE == 1) {
      int cc = c & 127;
      const float* gg = (c < 128) ? g0 : g1;
      const float* bb = (c < 128) ? b0 : b1;
      const float* mm = (c < 128) ? m0 : m1;
      const float* vv = (c < 128) ? v0 : v1;
      float s = gg[cc] * rsqrtf(vv[cc] + 1e-5f);
      sh = bb[cc] - mm[cc] * s;
    } else {
      float s0 = g0[c] * rsqrtf(v0[c] + 1e-5f);
      float s1 = g1[c] * rsqrtf(v1[c] + 1e-5f);
      sh = (b0[c] - m0[c] * s0) + (b1[c] - m1[c] * s1);
    }
    #pragma unroll
    for (int mi = 0; mi < 4; mi++) {
      int px = wm * 64 + mi * 16 + lk * 4;
      float4v v = acc[mi][ni];
      v.x = fmaxf(v.x + sh, 0.0f);
      v.y = fmaxf(v.y + sh, 0.0f);
      v.z = fmaxf(v.z + sh, 0.0f);
      v.w = fmaxf(v.w + sh, 0.0f);
      if (OUT_F32) {
        float* ob = (float*)out0;
        *(float4v*)(ob + ((size_t)b * 256 + c) * HWSZ + (size_t)h * WW + px) = v;
      } else if (SPLIT_OUT) {
        short* ob = (short*)((c < 128) ? out0 : out1);
        size_t base = (((size_t)b * HH + h) * WW + px) * 128 + (c & 127);
        ob[base      ] = f2bf(v.x);
        ob[base + 128 ] = f2bf(v.y);
        ob[base + 256 ] = f2bf(v.z);
        ob[base + 384 ] = f2bf(v.w);
      } else {
        short* ob = (short*)out0;
        size_t base = (((size_t)b * HH + h) * WW + px) * 256 + c;
        ob[base      ] = f2bf(v.x);
        ob[base + 256 ] = f2bf(v.y);
        ob[base + 512 ] = f2bf(v.z);
        ob[base + 768 ] = f2bf(v.w);
      }
    }
  }
}

// ---------------- reverse cummax over H on bf16 NHWC [b][h][w][128], in place ----
// v5: 8-segment parallel scan, uint2 (4 bf16) per thread. One block per (w, b)
// -> 512 blocks (2/CU). Thread = (seg 0..7, quad cq 0..31); each scans 16 h into
// registers (serial depth 16), then applies the suffix max of later segments via
// LDS. All max arithmetic in the bf16-representable domain -> bit-identical.
__global__ __launch_bounds__(256) void colscan_kernel(unsigned* __restrict__ p) {
  __shared__ float sm[8][4][32];
  const int t = threadIdx.x;
  const int seg = t >> 5, cq = t & 31;
  const int w = blockIdx.x;
  const int b = blockIdx.y;
  const uint2v* __restrict__ pv = (const uint2v*)p;
  uint2v* __restrict__ pvw = (uint2v*)p;
  const size_t colbase = ((size_t)b * HH * WW + w) * 32 + cq;   // uint2 units; + h*(WW*32)
  float m0 = -INFINITY, m1 = -INFINITY, m2 = -INFINITY, m3 = -INFINITY;
  uint2v r[16];
  const int htop = seg * 16 + 15;
  #pragma unroll
  for (int i = 0; i < 16; i++) {
    int h = htop - i;
    uint2v u = pv[colbase + (size_t)h * (WW * 32)];
    m0 = fmaxf(m0, bf2f((unsigned short)(u.x & 0xffff)));
    m1 = fmaxf(m1, bf2f((unsigned short)(u.x >> 16)));
    m2 = fmaxf(m2, bf2f((unsigned short)(u.y & 0xffff)));
    m3 = fmaxf(m3, bf2f((unsigned short)(u.y >> 16)));
    uint2v o;
    o.x = ((unsigned)(unsigned short)f2bf(m1) << 16) | (unsigned short)f2bf(m0);
    o.y = ((unsigned)(unsigned short)f2bf(m3) << 16) | (unsigned short)f2bf(m2);
    r[i] = o;
  }
  sm[seg][0][cq] = m0;
  sm[seg][1][cq] = m1;
  sm[seg][2][cq] = m2;
  sm[seg][3][cq] = m3;
  __syncthreads();
  float s0 = -INFINITY, s1 = -INFINITY, s2 = -INFINITY, s3 = -INFINITY;
  #pragma unroll
  for (int s = 0; s < 7; s++) {
    if (seg + 1 + s < 8) {
      s0 = fmaxf(s0, sm[seg + 1 + s][0][cq]);
      s1 = fmaxf(s1, sm[seg + 1 + s][1][cq]);
      s2 = fmaxf(s2, sm[seg + 1 + s][2][cq]);
      s3 = fmaxf(s3, sm[seg + 1 + s][3][cq]);
    }
  }
  #pragma unroll
  for (int i = 0; i < 16; i++) {
    int h = htop - i;
    float f0 = fmaxf(bf2f((unsigned short)(r[i].x & 0xffff)), s0);
    float f1 = fmaxf(bf2f((unsigned short)(r[i].x >> 16)), s1);
    float f2 = fmaxf(bf2f((unsigned short)(r[i].y & 0xffff)), s2);
    float f3 = fmaxf(bf2f((unsigned short)(r[i].y >> 16)), s3);
    uint2v o;
    o.x = ((unsigned)(unsigned short)f2bf(f1) << 16) | (unsigned short)f2bf(f0);
    o.y = ((unsigned)(unsigned short)f2bf(f3) << 16) | (unsigned short)f2bf(f2);
    pvw[colbase + (size_t)h * (WW * 32)] = o;
  }
}

// ---------------- reverse cummax over W on p2 + add p1 -> p1 (bf16 NHWC C=128) ----
// v4: scan phase on a FLOAT LDS tile [128][129] (conflict-free; no bf16<->f32
// converts in the 64-deep dependent chain). 2 segs x 128 ch; seg-0 fixed during
// the add pass with seg-1's boundary max. Values stay bf16-representable ->
// bit-identical to v1.
__global__ __launch_bounds__(256) void rowscan_add_kernel(
    const short* __restrict__ p2, short* __restrict__ p1) {
  __shared__ float pf[128 * 129];
  __shared__ float bm[128];
  const int tid = threadIdx.x;
  const int hb = blockIdx.x;
  const int b  = blockIdx.y;
  const size_t base = (((size_t)b * HH + hb) * WW) * 128;

  #pragma unroll
  for (int i = 0; i < 8; i++) {
    int idx = tid + i * 256;          // granule of 8 shorts; w = idx>>4, g = idx&15
    int w = idx >> 4, g = idx & 15;
    short8 v = *(const short8*)(p2 + base + (size_t)idx * 8);
    #pragma unroll
    for (int j = 0; j < 8; j++) pf[w * 129 + g * 8 + j] = bf2f((unsigned short)v[j]);
  }
  __syncthreads();
  {
    const int seg = tid >> 7;         // 0: w 0..63, 1: w 64..127
    const int c = tid & 127;
    float m = -INFINITY;
    const int wtop = seg * 64 + 63;
    for (int i = 0; i < 64; i++) {
      int a = (wtop - i) * 129 + c;
      m = fmaxf(m, pf[a]);
      pf[a] = m;
    }
    if (seg) bm[c] = m;               // max over w = 64..127
  }
  __syncthreads();
  #pragma unroll
  for (int i = 0; i < 8; i++) {
    int idx = tid + i * 256;
    int w = idx >> 4, g = idx & 15;
    short8 ov = *(const short8*)(p1 + base + (size_t)idx * 8);
    short8 rv;
    if (w < 64) {
      #pragma unroll
      for (int j = 0; j < 8; j++) {
        float f = fmaxf(pf[w * 129 + g * 8 + j], bm[g * 8 + j]);
        rv[j] = f2bf(f + bf2f((unsigned short)ov[j]));
      }
    } else {
      #pragma unroll
      for (int j = 0; j < 8; j++)
        rv[j] = f2bf(pf[w * 129 + g * 8 + j] + bf2f((unsigned short)ov[j]));
    }
    *(short8*)(p1 + base + (size_t)idx * 8) = rv;
  }
}

extern "C" void kernel_launch(void* const* d_in, const int* in_sizes, int n_in,
                              void* d_out, int out_size, void* d_ws, size_t ws_size,
                              hipStream_t stream) {
  const float* x    = (const float*)d_in[0];
  const float* w_p1 = (const float*)d_in[1];
  const float* g_p1 = (const float*)d_in[2];
  const float* b_p1 = (const float*)d_in[3];
  const float* m_p1 = (const float*)d_in[4];
  const float* v_p1 = (const float*)d_in[5];
  const float* w_p2 = (const float*)d_in[6];
  const float* g_p2 = (const float*)d_in[7];
  const float* b_p2 = (const float*)d_in[8];
  const float* m_p2 = (const float*)d_in[9];
  const float* v_p2 = (const float*)d_in[10];
  const float* w_c1 = (const float*)d_in[11];
  const float* g_c1 = (const float*)d_in[12];
  const float* b_c1 = (const float*)d_in[13];
  const float* m_c1 = (const float*)d_in[14];
  const float* v_c1 = (const float*)d_in[15];
  const float* w_c2 = (const float*)d_in[16];
  const float* g_c2 = (const float*)d_in[17];
  const float* b_c2 = (const float*)d_in[18];
  const float* m_c2 = (const float*)d_in[19];
  const float* v_c2 = (const float*)d_in[20];
  const float* w_p3 = (const float*)d_in[21];
  const float* g_p3 = (const float*)d_in[22];
  const float* b_p3 = (const float*)d_in[23];
  const float* m_p3 = (const float*)d_in[24];
  const float* v_p3 = (const float*)d_in[25];

  char* ws = (char*)d_ws;
  // Persistent tensors — total exactly 100,663,296 B.
  short* p1  = (short*)(ws + 0);          // bf16 NHWC [4][128][128][128]  16 MB
  short* p2  = (short*)(ws + 16777216);   // bf16 NHWC [4][128][128][128]  16 MB
  short* r   = (short*)(ws + 33554432);   // bf16 NHWC [4][128][128][256]  32 MB
  short* xbf = (short*)(ws + 67108864);   // bf16 NHWC [4][128][128][256]  32 MB
  // Weight buffers overlay dead regions (stream-ordered):
  short* wb12 = r;                        // [9][256][256]; dead before c1 writes r
  short* wbc1 = p2;                       // [9][256][128]; written after rowscan_add
  short* wbc2 = (short*)(ws + 16777216 + 589824);            // [256][256]
  short* wbp3 = (short*)(ws + 16777216 + 589824 + 131072);   // [9][256][256], also in p2

  // x -> NHWC bf16  +  weights for p1|p2 (fused)
  prep1_kernel<<<dim3(2816), 256, 0, stream>>>(x, xbf,
      w_p1, g_p1, v_p1, w_p2, g_p2, v_p2, wb12);

  // p1|p2 = relu(bn(conv3x3(x)))
  conv_mfma<256, false, 1, true, false><<<dim3(512), 256, 0, stream>>>(
      xbf, nullptr, wb12, nullptr,
      g_p1, b_p1, m_p1, v_p1, g_p2, b_p2, m_p2, v_p2, (void*)p1, (void*)p2);

  // corner pooling: cp1 in-place on p1, then s = rowscan(p2) + cp1 -> p1
  colscan_kernel<<<dim3(128, 4), 256, 0, stream>>>((unsigned*)p1);
  rowscan_add_kernel<<<dim3(128, 4), 256, 0, stream>>>(p2, p1);

  // weights for c1 (3x3), c2 (1x1), p3 (3x3) into p2 region (p2 dead now) — fused
  prep2_kernel<<<dim3(3712), 256, 0, stream>>>(
      w_c1, g_c1, v_c1, w_c2, g_c2, v_c2, w_p3, g_p3, v_p3, wbc1, wbc2, wbp3);

  // r = relu(bn1(conv3x3(s)) + bn2(conv1x1(x)))
  conv_mfma<128, true, 2, false, false><<<dim3(512), 256, 0, stream>>>(
      p1, xbf, wbc1, wbc2,
      g_c1, b_c1, m_c1, v_c1, g_c2, b_c2, m_c2, v_c2, (void*)r, nullptr);

  // out = relu(bn(conv3x3(r)))  — fp32 NCHW float4 stores
  conv_mfma<256, false, 0, false, true><<<dim3(512), 256, 0, stream>>>(
      r, nullptr, wbp3, nullptr,
      g_p3, b_p3, m_p3, v_p3, nullptr, nullptr, nullptr, nullptr, d_out, nullptr);
}